// Round 1
// baseline (2032.330 us; speedup 1.0000x reference)
//
#include <hip/hip_runtime.h>
#include <hip/hip_bf16.h>
#include <cstdint>

// Problem constants
#define SS 512
#define OBS_N 32000
#define TT 1024
#define BB 64

// Main-kernel tiling: 8 waves of 64 lanes.
// E (f16 pair-packed along i) rows 0..383 live in registers (24 i-pairs/wave),
// rows 384..511 live in LDS (8 i-pairs/wave).
#define RPW 24
#define LDS_I2 64
#define LPW 8

typedef _Float16 h2 __attribute__((ext_vector_type(2)));

static __device__ __forceinline__ float wave_max(float v) {
#pragma unroll
  for (int m = 32; m >= 1; m >>= 1) v = fmaxf(v, __shfl_xor(v, m, 64));
  return v;
}
static __device__ __forceinline__ float wave_sum(float v) {
#pragma unroll
  for (int m = 32; m >= 1; m >>= 1) v += __shfl_xor(v, m, 64);
  return v;
}

// ---------------- Prep 1: row logsumexp of observation_transitions [512 x 32000]
__global__ __launch_bounds__(256) void prep_obs_lse(const float* __restrict__ ot,
                                                    float* __restrict__ lse) {
  const int s = blockIdx.x;
  const int tid = threadIdx.x;
  const float4* row = (const float4*)(ot + (size_t)s * OBS_N);
  __shared__ float redm[4];
  __shared__ float reds[4];

  float m = -INFINITY;
  for (int k = tid; k < OBS_N / 4; k += 256) {
    float4 v = row[k];
    m = fmaxf(m, fmaxf(fmaxf(v.x, v.y), fmaxf(v.z, v.w)));
  }
  m = wave_max(m);
  if ((tid & 63) == 0) redm[tid >> 6] = m;
  __syncthreads();
  m = fmaxf(fmaxf(redm[0], redm[1]), fmaxf(redm[2], redm[3]));

  float ssum = 0.f;
  for (int k = tid; k < OBS_N / 4; k += 256) {
    float4 v = row[k];
    ssum += __expf(v.x - m) + __expf(v.y - m) + __expf(v.z - m) + __expf(v.w - m);
  }
  ssum = wave_sum(ssum);
  if ((tid & 63) == 0) reds[tid >> 6] = ssum;
  __syncthreads();
  if (tid == 0) {
    float s4 = reds[0] + reds[1] + reds[2] + reds[3];
    lse[s] = m + __logf(s4);
  }
}

// ---------------- Prep 2: E = softmax rows of state_transitions, f16, packed in
// pairs along i: EP[i2][j] = (f16 E[2*i2][j]) | (f16 E[2*i2+1][j] << 16)
__global__ __launch_bounds__(512) void prep_trans(const float* __restrict__ st,
                                                  uint32_t* __restrict__ EP) {
  const int r = blockIdx.x;  // handles rows 2r and 2r+1
  const int j = threadIdx.x;
  const int wv = j >> 6;
  float a0 = st[(size_t)(2 * r) * SS + j];
  float a1 = st[(size_t)(2 * r + 1) * SS + j];

  __shared__ float w0[8], w1[8], s0a[8], s1a[8];
  float m0 = wave_max(a0), m1 = wave_max(a1);
  if ((j & 63) == 0) { w0[wv] = m0; w1[wv] = m1; }
  __syncthreads();
  m0 = w0[0]; m1 = w1[0];
#pragma unroll
  for (int q = 1; q < 8; ++q) { m0 = fmaxf(m0, w0[q]); m1 = fmaxf(m1, w1[q]); }

  float e0 = __expf(a0 - m0), e1 = __expf(a1 - m1);
  float s0 = wave_sum(e0), s1 = wave_sum(e1);
  if ((j & 63) == 0) { s0a[wv] = s0; s1a[wv] = s1; }
  __syncthreads();
  s0 = 0.f; s1 = 0.f;
#pragma unroll
  for (int q = 0; q < 8; ++q) { s0 += s0a[q]; s1 += s1a[q]; }

  _Float16 h0 = (_Float16)(e0 / s0);
  _Float16 h1 = (_Float16)(e1 / s1);
  uint32_t u = ((uint32_t)__builtin_bit_cast(unsigned short, h1) << 16) |
               (uint32_t)__builtin_bit_cast(unsigned short, h0);
  EP[(size_t)r * SS + j] = u;
}

// ---------------- Prep 3: log_softmax of prior [512]
__global__ __launch_bounds__(512) void prep_prior(const float* __restrict__ pr,
                                                  float* __restrict__ lp) {
  const int j = threadIdx.x;
  const int wv = j >> 6;
  float a = pr[j];
  __shared__ float wm[8], ws[8];
  float m = wave_max(a);
  if ((j & 63) == 0) wm[wv] = m;
  __syncthreads();
  m = wm[0];
#pragma unroll
  for (int q = 1; q < 8; ++q) m = fmaxf(m, wm[q]);
  float e = __expf(a - m);
  float s = wave_sum(e);
  if ((j & 63) == 0) ws[wv] = s;
  __syncthreads();
  s = 0.f;
#pragma unroll
  for (int q = 0; q < 8; ++q) s += ws[q];
  lp[j] = a - m - __logf(s);
}

// ---------------- Main: one workgroup per batch chain, 8 waves.
__global__ __launch_bounds__(512, 2) void hmm_main(
    const uint32_t* __restrict__ EP, const float* __restrict__ lse_obs,
    const float* __restrict__ lp, const int* __restrict__ obs,
    const float* __restrict__ ot, float* __restrict__ out) {
  // LDS: E tail rows as [i2'][lane][k] so per-lane k-reads are contiguous (b128-able)
  __shared__ uint32_t eL[LDS_I2][64][8];   // 128 KiB
  __shared__ uint32_t ph32[SS / 2];        // f16 P pairs, 1 KiB
  __shared__ float pp[8][SS];              // per-wave partial sums, 16 KiB
  __shared__ float wred[8];
  __shared__ float wsum[8];

  const int tid = threadIdx.x;
  const int w = tid >> 6;
  const int l = tid & 63;
  const int b = blockIdx.x;
  const int j = tid;  // column ownership for scalar phases

  // Load register-resident E: wave w holds i-pairs [24w, 24w+24), lane l cols {l+64k}
  uint32_t eR[RPW * 8];
#pragma unroll
  for (int p = 0; p < RPW; ++p)
#pragma unroll
    for (int k = 0; k < 8; ++k)
      eR[p * 8 + k] = EP[(size_t)(RPW * w + p) * SS + k * 64 + l];

  // Stage LDS-resident E rows (global i2 = 192..255)
  for (int q = 0; q < LDS_I2; ++q)
    eL[q][tid & 63][tid >> 6] = EP[(size_t)(192 + q) * SS + tid];

  const float lse_j = lse_obs[j];
  const float lpj = lp[j];
  const float* base_ot = ot + (size_t)j * OBS_N;
  const int* orow = obs + b * TT;

  const int o0 = orow[0];
  float alpha = base_ot[o0] - lse_j + lpj;

  int on = orow[1];
  float ot_next = base_ot[on];  // obs column value for step 1 (prefetched)

  __syncthreads();  // eL ready

  for (int t = 1; t <= TT; ++t) {
    // Prefetch obs column value for step t+1 (terminal obs = 0 at t = TT)
    int o2 = (t <= TT - 2) ? orow[t + 1] : 0;
    float ot_pf = (t < TT) ? base_ot[o2] : 0.f;

    // M = max over all 512 alphas
    float m = wave_max(alpha);
    if (l == 0) wred[w] = m;
    __syncthreads();
    float M = wred[0];
#pragma unroll
    for (int q = 1; q < 8; ++q) M = fmaxf(M, wred[q]);

    // P = exp(alpha - M) as f16, shared via LDS
    float Pj = __expf(alpha - M);
    reinterpret_cast<unsigned short*>(ph32)[j] =
        __builtin_bit_cast(unsigned short, (_Float16)Pj);
    __syncthreads();

    // Dot phase: acc[k] (k-th owned column) over this wave's 64 rows
    h2 acc[8] = {};
#pragma unroll
    for (int p = 0; p < RPW; ++p) {
      h2 phv = __builtin_bit_cast(h2, ph32[RPW * w + p]);
#pragma unroll
      for (int k = 0; k < 8; ++k) {
        h2 ev = __builtin_bit_cast(h2, eR[p * 8 + k]);
        acc[k] += phv * ev;  // v_pk_fma_f16
      }
    }
#pragma unroll
    for (int q = 0; q < LPW; ++q) {
      h2 phv = __builtin_bit_cast(h2, ph32[192 + LPW * w + q]);
#pragma unroll
      for (int k = 0; k < 8; ++k) {
        h2 ev = __builtin_bit_cast(h2, eL[LPW * w + q][l][k]);
        acc[k] += phv * ev;
      }
    }
#pragma unroll
    for (int k = 0; k < 8; ++k)
      pp[w][k * 64 + l] = (float)acc[k].x + (float)acc[k].y;
    __syncthreads();

    // Combine 8 wave-partials, finish the step
    float pred = 0.f;
#pragma unroll
    for (int q = 0; q < 8; ++q) pred += pp[q][j];
    alpha = M + __logf(pred) + (ot_next - lse_j);
    ot_next = ot_pf;
  }

  // Final logsumexp over states
  float m = wave_max(alpha);
  if (l == 0) wred[w] = m;
  __syncthreads();
  float M = wred[0];
#pragma unroll
  for (int q = 1; q < 8; ++q) M = fmaxf(M, wred[q]);
  float e = __expf(alpha - M);
  float s = wave_sum(e);
  if (l == 0) wsum[w] = s;
  __syncthreads();
  if (tid == 0) {
    float tot = 0.f;
#pragma unroll
    for (int q = 0; q < 8; ++q) tot += wsum[q];
    out[b] = M + __logf(tot);
  }
}

extern "C" void kernel_launch(void* const* d_in, const int* in_sizes, int n_in,
                              void* d_out, int out_size, void* d_ws, size_t ws_size,
                              hipStream_t stream) {
  const int* obs = (const int*)d_in[0];        // [64, 1024] int32
  const float* st = (const float*)d_in[1];     // [512, 512] f32
  const float* ot = (const float*)d_in[2];     // [512, 32000] f32
  const float* pr = (const float*)d_in[3];     // [512] f32
  float* out = (float*)d_out;                  // [64] f32

  char* ws = (char*)d_ws;
  uint32_t* EP = (uint32_t*)ws;                     // 512 KiB
  float* lse_obs = (float*)(ws + 524288);           // 2 KiB
  float* lprior = (float*)(ws + 524288 + 2048);     // 2 KiB

  prep_obs_lse<<<SS, 256, 0, stream>>>(ot, lse_obs);
  prep_trans<<<SS / 2, SS, 0, stream>>>(st, EP);
  prep_prior<<<1, SS, 0, stream>>>(pr, lprior);
  hmm_main<<<BB, SS, 0, stream>>>(EP, lse_obs, lprior, obs, ot, out);
}

// Round 3
// 1864.066 us; speedup vs baseline: 1.0903x; 1.0903x over previous
//
#include <hip/hip_runtime.h>
#include <hip/hip_bf16.h>
#include <cstdint>

// Problem constants
#define SS 512
#define OBS_N 32000
#define TT 1024
#define BB 64

// Main-kernel tiling: 8 waves of 64 lanes. Wave w owns rows [64w, 64w+64)
// = f16-pair rows [32w, 32w+32): first 24 pairs in VGPRs, last 8 in LDS.
#define RPW 24
#define TPW 8

typedef _Float16 h2 __attribute__((ext_vector_type(2)));

static __device__ __forceinline__ float wave_max(float v) {
#pragma unroll
  for (int m = 32; m >= 1; m >>= 1) v = fmaxf(v, __shfl_xor(v, m, 64));
  return v;
}
static __device__ __forceinline__ float wave_sum(float v) {
#pragma unroll
  for (int m = 32; m >= 1; m >>= 1) v += __shfl_xor(v, m, 64);
  return v;
}

// Fast full-wave max via DPP (canonical GCN reduce: result in lane 63, then
// broadcast with readlane). old=self so masked-out lanes keep identity.
static __device__ __forceinline__ float wave_max_dpp(float x) {
  int v = __builtin_bit_cast(int, x);
#define DPP_STEP(ctrl)                                                        \
  {                                                                           \
    int t = __builtin_amdgcn_update_dpp(v, v, (ctrl), 0xf, 0xf, false);       \
    v = __builtin_bit_cast(                                                   \
        int, fmaxf(__builtin_bit_cast(float, v), __builtin_bit_cast(float, t)));\
  }
  DPP_STEP(0x111)  // row_shr:1
  DPP_STEP(0x112)  // row_shr:2
  DPP_STEP(0x114)  // row_shr:4
  DPP_STEP(0x118)  // row_shr:8
  DPP_STEP(0x142)  // row_bcast:15
  DPP_STEP(0x143)  // row_bcast:31
#undef DPP_STEP
  return __builtin_bit_cast(float, __builtin_amdgcn_readlane(v, 63));
}

static __device__ __forceinline__ float dot2f(h2 a, h2 b, float c) {
#if __has_builtin(__builtin_amdgcn_fdot2)
  return __builtin_amdgcn_fdot2(a, b, c, false);
#else
  return c + (float)a.x * (float)b.x + (float)a.y * (float)b.y;
#endif
}

static __device__ __forceinline__ h2 as_h2(uint32_t u) {
  return __builtin_bit_cast(h2, u);
}
static __device__ __forceinline__ uint32_t sel4(const uint4& v, int s) {
  return s == 0 ? v.x : s == 1 ? v.y : s == 2 ? v.z : v.w;
}

// ---------------- Prep 1: row logsumexp of observation_transitions [512 x 32000]
__global__ __launch_bounds__(256) void prep_obs_lse(const float* __restrict__ ot,
                                                    float* __restrict__ lse) {
  const int s = blockIdx.x;
  const int tid = threadIdx.x;
  const float4* row = (const float4*)(ot + (size_t)s * OBS_N);
  __shared__ float redm[4];
  __shared__ float reds[4];

  float m = -INFINITY;
  for (int k = tid; k < OBS_N / 4; k += 256) {
    float4 v = row[k];
    m = fmaxf(m, fmaxf(fmaxf(v.x, v.y), fmaxf(v.z, v.w)));
  }
  m = wave_max(m);
  if ((tid & 63) == 0) redm[tid >> 6] = m;
  __syncthreads();
  m = fmaxf(fmaxf(redm[0], redm[1]), fmaxf(redm[2], redm[3]));

  float ssum = 0.f;
  for (int k = tid; k < OBS_N / 4; k += 256) {
    float4 v = row[k];
    ssum += __expf(v.x - m) + __expf(v.y - m) + __expf(v.z - m) + __expf(v.w - m);
  }
  ssum = wave_sum(ssum);
  if ((tid & 63) == 0) reds[tid >> 6] = ssum;
  __syncthreads();
  if (tid == 0) {
    float s4 = reds[0] + reds[1] + reds[2] + reds[3];
    lse[s] = m + __logf(s4);
  }
}

// ---------------- Prep 2: E = softmax rows of state_transitions, f16, packed in
// pairs along i: EP[i2][j] = (f16 E[2*i2][j]) | (f16 E[2*i2+1][j] << 16)
__global__ __launch_bounds__(512) void prep_trans(const float* __restrict__ st,
                                                  uint32_t* __restrict__ EP) {
  const int r = blockIdx.x;  // handles rows 2r and 2r+1
  const int j = threadIdx.x;
  const int wv = j >> 6;
  float a0 = st[(size_t)(2 * r) * SS + j];
  float a1 = st[(size_t)(2 * r + 1) * SS + j];

  __shared__ float w0[8], w1[8], s0a[8], s1a[8];
  float m0 = wave_max(a0), m1 = wave_max(a1);
  if ((j & 63) == 0) { w0[wv] = m0; w1[wv] = m1; }
  __syncthreads();
  m0 = w0[0]; m1 = w1[0];
#pragma unroll
  for (int q = 1; q < 8; ++q) { m0 = fmaxf(m0, w0[q]); m1 = fmaxf(m1, w1[q]); }

  float e0 = __expf(a0 - m0), e1 = __expf(a1 - m1);
  float s0 = wave_sum(e0), s1 = wave_sum(e1);
  if ((j & 63) == 0) { s0a[wv] = s0; s1a[wv] = s1; }
  __syncthreads();
  s0 = 0.f; s1 = 0.f;
#pragma unroll
  for (int q = 0; q < 8; ++q) { s0 += s0a[q]; s1 += s1a[q]; }

  _Float16 h0 = (_Float16)(e0 / s0);
  _Float16 h1 = (_Float16)(e1 / s1);
  uint32_t u = ((uint32_t)__builtin_bit_cast(unsigned short, h1) << 16) |
               (uint32_t)__builtin_bit_cast(unsigned short, h0);
  EP[(size_t)r * SS + j] = u;
}

// ---------------- Prep 3: log_softmax of prior [512]
__global__ __launch_bounds__(512) void prep_prior(const float* __restrict__ pr,
                                                  float* __restrict__ lp) {
  const int j = threadIdx.x;
  const int wv = j >> 6;
  float a = pr[j];
  __shared__ float wm[8], ws[8];
  float m = wave_max(a);
  if ((j & 63) == 0) wm[wv] = m;
  __syncthreads();
  m = wm[0];
#pragma unroll
  for (int q = 1; q < 8; ++q) m = fmaxf(m, wm[q]);
  float e = __expf(a - m);
  float s = wave_sum(e);
  if ((j & 63) == 0) ws[wv] = s;
  __syncthreads();
  s = 0.f;
#pragma unroll
  for (int q = 0; q < 8; ++q) s += ws[q];
  lp[j] = a - m - __logf(s);
}

// ---------------- Main: one workgroup per batch chain, 8 waves, 1 barrier/step.
__global__ __launch_bounds__(512, 1) void hmm_main(
    const uint32_t* __restrict__ EP, const float* __restrict__ lse_obs,
    const float* __restrict__ lp, const int* __restrict__ obs,
    const float* __restrict__ ot, float* __restrict__ out) {
  // Tail E pairs, lane-contiguous 16B chunks: eL[tq][c][l][m] holds
  // EP[pairrow(tq)][(c*4+m)*64 + l]  -> wave64 ds_read_b128 is contiguous 1KiB.
  __shared__ uint32_t eL[64][2][64][4];            // 128 KiB
  __shared__ __align__(16) unsigned short ph16[SS];        // 1 KiB, wave-local
  __shared__ __align__(16) unsigned short ppb[2][8][SS];   // 16 KiB f16 partials
  __shared__ __align__(16) float wred[2][8];
  __shared__ float fin_m[8], fin_s[8];

  const int tid = threadIdx.x;
  const int w = tid >> 6;
  const int l = tid & 63;
  const int b = blockIdx.x;
  const int j = tid;  // column ownership for scalar phases

  // Register-resident E: wave w pairs [32w, 32w+24), lane l cols {l+64k}
  uint32_t eR[RPW * 8];
#pragma unroll
  for (int p = 0; p < RPW; ++p)
#pragma unroll
    for (int k = 0; k < 8; ++k)
      eR[p * 8 + k] = EP[(size_t)(32 * w + p) * SS + k * 64 + l];

  // Stage LDS tail pairs: tq = 8*w' + q -> pair row 32*w' + 24 + q
  for (int idx = tid; idx < 64 * 2 * 64; idx += 512) {
    int tq = idx >> 7;
    int c = (idx >> 6) & 1;
    int ll = idx & 63;
    int pr = 32 * (tq >> 3) + RPW + (tq & 7);
    const uint32_t* src = EP + (size_t)pr * SS + c * 256 + ll;
    eL[tq][c][ll][0] = src[0];
    eL[tq][c][ll][1] = src[64];
    eL[tq][c][ll][2] = src[128];
    eL[tq][c][ll][3] = src[192];
  }

  const float lse_j = lse_obs[j];
  const float lpj = lp[j];
  const float* base_ot = ot + (size_t)j * OBS_N;
  const int* orow = obs + b * TT;

  const int o0 = orow[0];
  float alpha = base_ot[o0] - lse_j + lpj;

  int on = orow[1];
  float otv = base_ot[on];  // obs value for step 1 (prefetched)

  __syncthreads();  // eL ready

  for (int t = 1; t <= TT; ++t) {
    const int par = t & 1;

    // Prefetch obs value for step t+1 (terminal obs id = 0 at t = TT)
    int o2 = (t <= TT - 2) ? orow[t + 1] : 0;
    float ot_pf = (t < TT) ? base_ot[o2] : 0.f;

    // Per-wave max (no cross-wave barrier needed; rescaled after the dot)
    float mw = wave_max_dpp(alpha);
    if (l == 0) wred[par][w] = mw;

    // P = exp(alpha - mw) as f16, wave-local through LDS (wave is lockstep)
    float Pj = __expf(alpha - mw);
    ph16[j] = __builtin_bit_cast(unsigned short, (_Float16)Pj);
    __builtin_amdgcn_wave_barrier();

    float acc[8] = {0.f, 0.f, 0.f, 0.f, 0.f, 0.f, 0.f, 0.f};

    // LDS tail first (issue b128 reads early): pairs 24..31 of this wave
#pragma unroll
    for (int qg = 0; qg < 2; ++qg) {
      uint4 ph4 = *(const uint4*)&ph16[64 * w + 48 + 8 * qg];
#pragma unroll
      for (int s = 0; s < 4; ++s) {
        const int q = 4 * qg + s;
        h2 phv = as_h2(sel4(ph4, s));
        const uint4 c0 = *(const uint4*)&eL[w * 8 + q][0][l][0];
        const uint4 c1 = *(const uint4*)&eL[w * 8 + q][1][l][0];
        acc[0] = dot2f(phv, as_h2(c0.x), acc[0]);
        acc[1] = dot2f(phv, as_h2(c0.y), acc[1]);
        acc[2] = dot2f(phv, as_h2(c0.z), acc[2]);
        acc[3] = dot2f(phv, as_h2(c0.w), acc[3]);
        acc[4] = dot2f(phv, as_h2(c1.x), acc[4]);
        acc[5] = dot2f(phv, as_h2(c1.y), acc[5]);
        acc[6] = dot2f(phv, as_h2(c1.z), acc[6]);
        acc[7] = dot2f(phv, as_h2(c1.w), acc[7]);
      }
    }

    // Register part: pairs 0..23 of this wave
#pragma unroll
    for (int g = 0; g < 6; ++g) {
      uint4 ph4 = *(const uint4*)&ph16[64 * w + 8 * g];
#pragma unroll
      for (int s = 0; s < 4; ++s) {
        const int p = 4 * g + s;
        h2 phv = as_h2(sel4(ph4, s));
#pragma unroll
        for (int k = 0; k < 8; ++k)
          acc[k] = dot2f(phv, as_h2(eR[p * 8 + k]), acc[k]);
      }
    }

    // Publish f16 partials
#pragma unroll
    for (int k = 0; k < 8; ++k)
      ppb[par][w][k * 64 + l] =
          __builtin_bit_cast(unsigned short, (_Float16)acc[k]);

    __syncthreads();  // the ONLY barrier per step

    // Global max + rescaled combine
    const float4 wv0 = *(const float4*)&wred[par][0];
    const float4 wv1 = *(const float4*)&wred[par][4];
    float M = fmaxf(fmaxf(fmaxf(wv0.x, wv0.y), fmaxf(wv0.z, wv0.w)),
                    fmaxf(fmaxf(wv1.x, wv1.y), fmaxf(wv1.z, wv1.w)));
    float earg = wred[par][l & 7];
    float ee = __expf(earg - M);  // lane q<8 holds exp(M_q - M)

    float pred = 0.f;
#pragma unroll
    for (int q = 0; q < 8; ++q) {
      float eq = __builtin_bit_cast(
          float, __builtin_amdgcn_readlane(__builtin_bit_cast(int, ee), q));
      float pq = (float)__builtin_bit_cast(_Float16, ppb[par][q][j]);
      pred = fmaf(eq, pq, pred);
    }
    alpha = M + __logf(pred) + (otv - lse_j);
    otv = ot_pf;
  }

  // Final logsumexp over states
  float m = wave_max(alpha);
  if (l == 0) fin_m[w] = m;
  __syncthreads();
  float M = fin_m[0];
#pragma unroll
  for (int q = 1; q < 8; ++q) M = fmaxf(M, fin_m[q]);
  float e = __expf(alpha - M);
  float s = wave_sum(e);
  if (l == 0) fin_s[w] = s;
  __syncthreads();
  if (tid == 0) {
    float tot = 0.f;
#pragma unroll
    for (int q = 0; q < 8; ++q) tot += fin_s[q];
    out[b] = M + __logf(tot);
  }
}

extern "C" void kernel_launch(void* const* d_in, const int* in_sizes, int n_in,
                              void* d_out, int out_size, void* d_ws, size_t ws_size,
                              hipStream_t stream) {
  const int* obs = (const int*)d_in[0];        // [64, 1024] int32
  const float* st = (const float*)d_in[1];     // [512, 512] f32
  const float* ot = (const float*)d_in[2];     // [512, 32000] f32
  const float* pr = (const float*)d_in[3];     // [512] f32
  float* out = (float*)d_out;                  // [64] f32

  char* ws = (char*)d_ws;
  uint32_t* EP = (uint32_t*)ws;                     // 512 KiB
  float* lse_obs = (float*)(ws + 524288);           // 2 KiB
  float* lprior = (float*)(ws + 524288 + 2048);     // 2 KiB

  prep_obs_lse<<<SS, 256, 0, stream>>>(ot, lse_obs);
  prep_trans<<<SS / 2, SS, 0, stream>>>(st, EP);
  prep_prior<<<1, SS, 0, stream>>>(pr, lprior);
  hmm_main<<<BB, SS, 0, stream>>>(EP, lse_obs, lprior, obs, ot, out);
}

// Round 4
// 1860.695 us; speedup vs baseline: 1.0922x; 1.0018x over previous
//
#include <hip/hip_runtime.h>
#include <hip/hip_bf16.h>
#include <cstdint>

// Problem constants
#define SS 512
#define OBS_N 32000
#define TT 1024
#define BB 64

// Main-kernel tiling: 8 waves of 64 lanes. Wave w owns rows [64w, 64w+64)
// = f16-pair rows [32w, 32w+32): first 24 pairs in VGPRs, last 8 in LDS.
#define RPW 24
#define TPW 8

typedef _Float16 h2 __attribute__((ext_vector_type(2)));

static __device__ __forceinline__ float wave_max(float v) {
#pragma unroll
  for (int m = 32; m >= 1; m >>= 1) v = fmaxf(v, __shfl_xor(v, m, 64));
  return v;
}
static __device__ __forceinline__ float wave_sum(float v) {
#pragma unroll
  for (int m = 32; m >= 1; m >>= 1) v += __shfl_xor(v, m, 64);
  return v;
}

// Fast full-wave max via DPP (result in lane 63, broadcast with readlane).
static __device__ __forceinline__ float wave_max_dpp(float x) {
  int v = __builtin_bit_cast(int, x);
#define DPP_STEP(ctrl)                                                        \
  {                                                                           \
    int t = __builtin_amdgcn_update_dpp(v, v, (ctrl), 0xf, 0xf, false);       \
    v = __builtin_bit_cast(                                                   \
        int, fmaxf(__builtin_bit_cast(float, v), __builtin_bit_cast(float, t)));\
  }
  DPP_STEP(0x111)  // row_shr:1
  DPP_STEP(0x112)  // row_shr:2
  DPP_STEP(0x114)  // row_shr:4
  DPP_STEP(0x118)  // row_shr:8
  DPP_STEP(0x142)  // row_bcast:15
  DPP_STEP(0x143)  // row_bcast:31
#undef DPP_STEP
  return __builtin_bit_cast(float, __builtin_amdgcn_readlane(v, 63));
}

static __device__ __forceinline__ float dot2f(h2 a, h2 b, float c) {
#if __has_builtin(__builtin_amdgcn_fdot2)
  return __builtin_amdgcn_fdot2(a, b, c, false);
#else
  return c + (float)a.x * (float)b.x + (float)a.y * (float)b.y;
#endif
}

static __device__ __forceinline__ h2 as_h2(uint32_t u) {
  return __builtin_bit_cast(h2, u);
}
static __device__ __forceinline__ uint32_t sel4(const uint4& v, int s) {
  return s == 0 ? v.x : s == 1 ? v.y : s == 2 ? v.z : v.w;
}

// ---------------- Prep 1: row logsumexp of observation_transitions [512 x 32000]
__global__ __launch_bounds__(256) void prep_obs_lse(const float* __restrict__ ot,
                                                    float* __restrict__ lse) {
  const int s = blockIdx.x;
  const int tid = threadIdx.x;
  const float4* row = (const float4*)(ot + (size_t)s * OBS_N);
  __shared__ float redm[4];
  __shared__ float reds[4];

  float m = -INFINITY;
  for (int k = tid; k < OBS_N / 4; k += 256) {
    float4 v = row[k];
    m = fmaxf(m, fmaxf(fmaxf(v.x, v.y), fmaxf(v.z, v.w)));
  }
  m = wave_max(m);
  if ((tid & 63) == 0) redm[tid >> 6] = m;
  __syncthreads();
  m = fmaxf(fmaxf(redm[0], redm[1]), fmaxf(redm[2], redm[3]));

  float ssum = 0.f;
  for (int k = tid; k < OBS_N / 4; k += 256) {
    float4 v = row[k];
    ssum += __expf(v.x - m) + __expf(v.y - m) + __expf(v.z - m) + __expf(v.w - m);
  }
  ssum = wave_sum(ssum);
  if ((tid & 63) == 0) reds[tid >> 6] = ssum;
  __syncthreads();
  if (tid == 0) {
    float s4 = reds[0] + reds[1] + reds[2] + reds[3];
    lse[s] = m + __logf(s4);
  }
}

// ---------------- Prep 1b: transpose obs table -> oT[o][j] (coalesced gather)
__global__ __launch_bounds__(256) void transpose_ot(const float* __restrict__ ot,
                                                    float* __restrict__ oT) {
  __shared__ float tile[32][33];
  const int o0 = blockIdx.x * 32;  // 1000 tiles along O (32000/32)
  const int j0 = blockIdx.y * 32;  // 16 tiles along S (512/32)
  const int tx = threadIdx.x & 31;
  const int ty = threadIdx.x >> 5;  // 0..7
#pragma unroll
  for (int r = 0; r < 32; r += 8)
    tile[ty + r][tx] = ot[(size_t)(j0 + ty + r) * OBS_N + (o0 + tx)];
  __syncthreads();
#pragma unroll
  for (int r = 0; r < 32; r += 8)
    oT[(size_t)(o0 + ty + r) * SS + (j0 + tx)] = tile[tx][ty + r];
}

// ---------------- Prep 2: E = softmax rows of state_transitions, f16, packed in
// pairs along i: EP[i2][j] = (f16 E[2*i2][j]) | (f16 E[2*i2+1][j] << 16)
__global__ __launch_bounds__(512) void prep_trans(const float* __restrict__ st,
                                                  uint32_t* __restrict__ EP) {
  const int r = blockIdx.x;  // handles rows 2r and 2r+1
  const int j = threadIdx.x;
  const int wv = j >> 6;
  float a0 = st[(size_t)(2 * r) * SS + j];
  float a1 = st[(size_t)(2 * r + 1) * SS + j];

  __shared__ float w0[8], w1[8], s0a[8], s1a[8];
  float m0 = wave_max(a0), m1 = wave_max(a1);
  if ((j & 63) == 0) { w0[wv] = m0; w1[wv] = m1; }
  __syncthreads();
  m0 = w0[0]; m1 = w1[0];
#pragma unroll
  for (int q = 1; q < 8; ++q) { m0 = fmaxf(m0, w0[q]); m1 = fmaxf(m1, w1[q]); }

  float e0 = __expf(a0 - m0), e1 = __expf(a1 - m1);
  float s0 = wave_sum(e0), s1 = wave_sum(e1);
  if ((j & 63) == 0) { s0a[wv] = s0; s1a[wv] = s1; }
  __syncthreads();
  s0 = 0.f; s1 = 0.f;
#pragma unroll
  for (int q = 0; q < 8; ++q) { s0 += s0a[q]; s1 += s1a[q]; }

  _Float16 h0 = (_Float16)(e0 / s0);
  _Float16 h1 = (_Float16)(e1 / s1);
  uint32_t u = ((uint32_t)__builtin_bit_cast(unsigned short, h1) << 16) |
               (uint32_t)__builtin_bit_cast(unsigned short, h0);
  EP[(size_t)r * SS + j] = u;
}

// ---------------- Prep 3: log_softmax of prior [512]
__global__ __launch_bounds__(512) void prep_prior(const float* __restrict__ pr,
                                                  float* __restrict__ lp) {
  const int j = threadIdx.x;
  const int wv = j >> 6;
  float a = pr[j];
  __shared__ float wm[8], ws[8];
  float m = wave_max(a);
  if ((j & 63) == 0) wm[wv] = m;
  __syncthreads();
  m = wm[0];
#pragma unroll
  for (int q = 1; q < 8; ++q) m = fmaxf(m, wm[q]);
  float e = __expf(a - m);
  float s = wave_sum(e);
  if ((j & 63) == 0) ws[wv] = s;
  __syncthreads();
  s = 0.f;
#pragma unroll
  for (int q = 0; q < 8; ++q) s += ws[q];
  lp[j] = a - m - __logf(s);
}

// ---------------- Main: one workgroup per batch chain, 8 waves, 1 barrier/step.
// amdgpu_waves_per_eu(2,2): block is 8 waves = exactly 2/SIMD (LDS caps at 1
// block/CU), so the allocator may use 512/2 = 256 VGPRs — eR must NOT spill.
__attribute__((amdgpu_waves_per_eu(2, 2))) __global__ void
__launch_bounds__(512) hmm_main(
    const uint32_t* __restrict__ EP, const float* __restrict__ lse_obs,
    const float* __restrict__ lp, const int* __restrict__ obs,
    const float* __restrict__ og, int sO, int sJ, float* __restrict__ out) {
  // Tail E pairs, lane-contiguous 16B chunks: eL[tq][c][l][m] holds
  // EP[pairrow(tq)][(c*4+m)*64 + l]  -> wave64 ds_read_b128 is contiguous 1KiB.
  __shared__ uint32_t eL[64][2][64][4];            // 128 KiB
  __shared__ __align__(16) unsigned short ph16[SS];        // 1 KiB, wave-local
  __shared__ __align__(16) unsigned short ppb[2][8][SS];   // 16 KiB f16 partials
  __shared__ __align__(16) float wred[2][8];
  __shared__ float fin_m[8], fin_s[8];

  const int tid = threadIdx.x;
  const int w = tid >> 6;
  const int l = tid & 63;
  const int b = blockIdx.x;
  const int j = tid;  // column ownership for scalar phases

  // Register-resident E: wave w pairs [32w, 32w+24), lane l cols {l+64k}
  uint32_t eR[RPW * 8];
#pragma unroll
  for (int p = 0; p < RPW; ++p)
#pragma unroll
    for (int k = 0; k < 8; ++k)
      eR[p * 8 + k] = EP[(size_t)(32 * w + p) * SS + k * 64 + l];

  // Stage LDS tail pairs: tq = 8*w' + q -> pair row 32*w' + 24 + q
  for (int idx = tid; idx < 64 * 2 * 64; idx += 512) {
    int tq = idx >> 7;
    int c = (idx >> 6) & 1;
    int ll = idx & 63;
    int pr = 32 * (tq >> 3) + RPW + (tq & 7);
    const uint32_t* src = EP + (size_t)pr * SS + c * 256 + ll;
    eL[tq][c][ll][0] = src[0];
    eL[tq][c][ll][1] = src[64];
    eL[tq][c][ll][2] = src[128];
    eL[tq][c][ll][3] = src[192];
  }

  const float lse_j = lse_obs[j];
  const float lpj = lp[j];
  const size_t jOff = (size_t)j * sJ;
  const int* orow = obs + b * TT;

  const int o0 = orow[0];
  float alpha = og[(size_t)o0 * sO + jOff] - lse_j + lpj;

  int on = orow[1];
  float otv = og[(size_t)on * sO + jOff];  // obs value for step 1 (prefetched)

  __syncthreads();  // eL ready

  for (int t = 1; t <= TT; ++t) {
    const int par = t & 1;

    // Prefetch obs value for step t+1 (terminal obs id = 0 at t = TT)
    int o2 = (t <= TT - 2) ? orow[t + 1] : 0;
    float ot_pf = (t < TT) ? og[(size_t)o2 * sO + jOff] : 0.f;

    // Per-wave max (no cross-wave barrier needed; rescaled after the dot)
    float mw = wave_max_dpp(alpha);
    if (l == 0) wred[par][w] = mw;

    // P = exp(alpha - mw) as f16, wave-local through LDS (wave is lockstep)
    float Pj = __expf(alpha - mw);
    ph16[j] = __builtin_bit_cast(unsigned short, (_Float16)Pj);
    __builtin_amdgcn_wave_barrier();

    float acc[8] = {0.f, 0.f, 0.f, 0.f, 0.f, 0.f, 0.f, 0.f};

    // LDS tail first (issue b128 reads early): pairs 24..31 of this wave
#pragma unroll
    for (int qg = 0; qg < 2; ++qg) {
      uint4 ph4 = *(const uint4*)&ph16[64 * w + 48 + 8 * qg];
#pragma unroll
      for (int s = 0; s < 4; ++s) {
        const int q = 4 * qg + s;
        h2 phv = as_h2(sel4(ph4, s));
        const uint4 c0 = *(const uint4*)&eL[w * 8 + q][0][l][0];
        const uint4 c1 = *(const uint4*)&eL[w * 8 + q][1][l][0];
        acc[0] = dot2f(phv, as_h2(c0.x), acc[0]);
        acc[1] = dot2f(phv, as_h2(c0.y), acc[1]);
        acc[2] = dot2f(phv, as_h2(c0.z), acc[2]);
        acc[3] = dot2f(phv, as_h2(c0.w), acc[3]);
        acc[4] = dot2f(phv, as_h2(c1.x), acc[4]);
        acc[5] = dot2f(phv, as_h2(c1.y), acc[5]);
        acc[6] = dot2f(phv, as_h2(c1.z), acc[6]);
        acc[7] = dot2f(phv, as_h2(c1.w), acc[7]);
      }
    }

    // Register part: pairs 0..23 of this wave
#pragma unroll
    for (int g = 0; g < 6; ++g) {
      uint4 ph4 = *(const uint4*)&ph16[64 * w + 8 * g];
#pragma unroll
      for (int s = 0; s < 4; ++s) {
        const int p = 4 * g + s;
        h2 phv = as_h2(sel4(ph4, s));
#pragma unroll
        for (int k = 0; k < 8; ++k)
          acc[k] = dot2f(phv, as_h2(eR[p * 8 + k]), acc[k]);
      }
    }

    // Publish f16 partials
#pragma unroll
    for (int k = 0; k < 8; ++k)
      ppb[par][w][k * 64 + l] =
          __builtin_bit_cast(unsigned short, (_Float16)acc[k]);

    __syncthreads();  // the ONLY barrier per step

    // Global max + rescaled combine
    const float4 wv0 = *(const float4*)&wred[par][0];
    const float4 wv1 = *(const float4*)&wred[par][4];
    float M = fmaxf(fmaxf(fmaxf(wv0.x, wv0.y), fmaxf(wv0.z, wv0.w)),
                    fmaxf(fmaxf(wv1.x, wv1.y), fmaxf(wv1.z, wv1.w)));
    float earg = wred[par][l & 7];
    float ee = __expf(earg - M);  // lane q<8 holds exp(M_q - M)

    float pred = 0.f;
#pragma unroll
    for (int q = 0; q < 8; ++q) {
      float eq = __builtin_bit_cast(
          float, __builtin_amdgcn_readlane(__builtin_bit_cast(int, ee), q));
      float pq = (float)__builtin_bit_cast(_Float16, ppb[par][q][j]);
      pred = fmaf(eq, pq, pred);
    }
    alpha = M + __logf(pred) + (otv - lse_j);
    otv = ot_pf;
  }

  // Final logsumexp over states
  float m = wave_max(alpha);
  if (l == 0) fin_m[w] = m;
  __syncthreads();
  float M = fin_m[0];
#pragma unroll
  for (int q = 1; q < 8; ++q) M = fmaxf(M, fin_m[q]);
  float e = __expf(alpha - M);
  float s = wave_sum(e);
  if (l == 0) fin_s[w] = s;
  __syncthreads();
  if (tid == 0) {
    float tot = 0.f;
#pragma unroll
    for (int q = 0; q < 8; ++q) tot += fin_s[q];
    out[b] = M + __logf(tot);
  }
}

extern "C" void kernel_launch(void* const* d_in, const int* in_sizes, int n_in,
                              void* d_out, int out_size, void* d_ws, size_t ws_size,
                              hipStream_t stream) {
  const int* obs = (const int*)d_in[0];        // [64, 1024] int32
  const float* st = (const float*)d_in[1];     // [512, 512] f32
  const float* ot = (const float*)d_in[2];     // [512, 32000] f32
  const float* pr = (const float*)d_in[3];     // [512] f32
  float* out = (float*)d_out;                  // [64] f32

  char* ws = (char*)d_ws;
  uint32_t* EP = (uint32_t*)ws;                     // 512 KiB
  float* lse_obs = (float*)(ws + 524288);           // 2 KiB
  float* lprior = (float*)(ws + 526336);            // 2 KiB
  float* oT = (float*)(ws + 528384);                // 65.5 MiB (optional)
  const size_t need = 528384 + (size_t)OBS_N * SS * sizeof(float);

  prep_obs_lse<<<SS, 256, 0, stream>>>(ot, lse_obs);
  prep_trans<<<SS / 2, SS, 0, stream>>>(st, EP);
  prep_prior<<<1, SS, 0, stream>>>(pr, lprior);

  const float* og = ot;
  int sO = 1, sJ = OBS_N;
  if (ws_size >= need) {
    transpose_ot<<<dim3(OBS_N / 32, SS / 32), 256, 0, stream>>>(ot, oT);
    og = oT; sO = SS; sJ = 1;
  }
  hmm_main<<<BB, SS, 0, stream>>>(EP, lse_obs, lprior, obs, og, sO, sJ, out);
}